// Round 5
// baseline (9637.944 us; speedup 1.0000x reference)
//
#include <hip/hip_runtime.h>
#include <hip/hip_bf16.h>
#include <math.h>

#define H 768
#define NB 2048
#define DD 16
#define NBLK 768
#define GSTRIDE (NBLK * 256)

typedef __attribute__((ext_vector_type(8))) short bf16x8;
typedef __attribute__((ext_vector_type(4))) float f32x4;

__device__ __forceinline__ void gload_lds16(const void* g, void* lds) {
  __builtin_amdgcn_global_load_lds((const __attribute__((address_space(1))) void*)g,
                                   (__attribute__((address_space(3))) void*)lds, 16, 0, 0);
}
__device__ __forceinline__ float b2f(short s) {
  union { unsigned int u; float f; } c;
  c.u = ((unsigned int)(unsigned short)s) << 16;
  return c.f;
}
__device__ __forceinline__ short f2bs(float f) {
  __hip_bfloat16 h = __float2bfloat16(f);
  return *(short*)&h;
}

struct KP {
  const float *observed, *emb_W, *emb_b;
  const float *e1_Wih, *e1_Whh, *e1_bih, *e1_bhh;
  const float *e2_Wih, *e2_Whh, *e2_bih, *e2_bhh;
  const float *dec_Wih, *dec_Whh, *dec_bih, *dec_bhh;
  const float *h2n_W, *h2n_b, *mix_W, *mix_b;
  __hip_bfloat16 *hp0, *hp1, *velall, *dvel, *Bp1, *Bp2, *Bp3, *B2g, *g2add;
  float *M1, *biasP;
  float *rel, *pred;
  int *bar;
};

// hierarchical device barrier: 16 group counters (48 arrivals each) -> master -> gen
__device__ __forceinline__ void gbar(int* bar) {
  __threadfence();
  __syncthreads();
  if (threadIdx.x == 0) {
    int* genp = bar + 272;
    int g = __hip_atomic_load(genp, __ATOMIC_RELAXED, __HIP_MEMORY_SCOPE_AGENT);
    bool done = false;
    int gid = blockIdx.x / 48;
    if (__hip_atomic_fetch_add(bar + gid * 16, 1, __ATOMIC_ACQ_REL, __HIP_MEMORY_SCOPE_AGENT) == 47) {
      __hip_atomic_store(bar + gid * 16, 0, __ATOMIC_RELAXED, __HIP_MEMORY_SCOPE_AGENT);
      if (__hip_atomic_fetch_add(bar + 256, 1, __ATOMIC_ACQ_REL, __HIP_MEMORY_SCOPE_AGENT) == 15) {
        __hip_atomic_store(bar + 256, 0, __ATOMIC_RELAXED, __HIP_MEMORY_SCOPE_AGENT);
        __hip_atomic_fetch_add(genp, 1, __ATOMIC_RELEASE, __HIP_MEMORY_SCOPE_AGENT);
        done = true;
      }
    }
    if (!done) {
      int t = 0;
      while (__hip_atomic_load(genp, __ATOMIC_ACQUIRE, __HIP_MEMORY_SCOPE_AGENT) == g &&
             t < (1 << 22)) {
        __builtin_amdgcn_s_sleep(2);
        ++t;
      }
    }
  }
  __syncthreads();
  __threadfence();
}

__global__ __launch_bounds__(256, 3) void k_all(KP P) {
  __shared__ __align__(16) char lds[49152];
  const int bid = blockIdx.x, tid = threadIdx.x;
  const int gtid = bid * 256 + tid;

  // ================= prep phase 1 =================
  // M1[s][g][d] = 4 * Wih_s[g][:256] . emb_W[:,d]
  for (int idx = gtid; idx < 3 * 2304 * 16; idx += GSTRIDE) {
    int d = idx & 15, g = (idx >> 4) % 2304, s = idx / (2304 * 16);
    const float* W = s == 0 ? P.e1_Wih : s == 1 ? P.e2_Wih : P.dec_Wih;
    int ld = s == 1 ? 1024 : 256;
    float sum = 0.f;
    for (int e = 0; e < 256; ++e) sum += W[(size_t)g * ld + e] * P.emb_W[e * 16 + d];
    P.M1[idx] = 4.0f * sum;
  }
  // packed bias [3][3072] with emb_b fold
  for (int idx = gtid; idx < 3 * 3072; idx += GSTRIDE) {
    int c = idx % 3072, s = idx / 3072;
    int f = (c >> 4) & 3, u = (c >> 6) * 16 + (c & 15);
    const float* W = s == 0 ? P.e1_Wih : s == 1 ? P.e2_Wih : P.dec_Wih;
    int ld = s == 1 ? 1024 : 256;
    const float* bi = s == 0 ? P.e1_bih : s == 1 ? P.e2_bih : P.dec_bih;
    const float* bh = s == 0 ? P.e1_bhh : s == 1 ? P.e2_bhh : P.dec_bhh;
    float v;
    if (f == 3) {
      v = bh[1536 + u];
    } else {
      int g = (f < 2 ? f * 768 : 1536) + u;
      float acc = bi[g] + (f < 2 ? bh[g] : 0.f);
      for (int e = 0; e < 256; ++e) acc += W[(size_t)g * ld + e] * P.emb_b[e];
      v = acc;
    }
    P.biasP[idx] = v;
  }
  // B2g: e2_Wih[:,256:] interleaved -> [3072][768]
  for (int idx = gtid; idx < 3072 * 768; idx += GSTRIDE) {
    int k = idx % 768, c = idx / 768;
    int f = (c >> 4) & 3, u = (c >> 6) * 16 + (c & 15);
    float v = (f < 3) ? P.e2_Wih[(size_t)(f * 768 + u) * 1024 + 256 + k] : 0.f;
    P.B2g[idx] = __float2bfloat16(v);
  }
  // velocities, 7 frames, padded to 32
  for (int idx = gtid; idx < 7 * 2048 * 32; idx += GSTRIDE) {
    int d = idx & 31, n = (idx >> 5) & 2047, s = idx >> 16;
    float v = 0.f;
    if (d < 16)
      v = P.observed[((size_t)(s + 1) * NB + n) * DD + d] -
          P.observed[((size_t)s * NB + n) * DD + d];
    P.velall[idx] = __float2bfloat16(v);
  }
  gbar(P.bar);
  // ================= prep phase 2: packB (needs M1) =================
  for (int idx = gtid; idx < 3 * 3072 * 800; idx += GSTRIDE) {
    int s = idx / (3072 * 800);
    int r = idx - s * (3072 * 800);
    const float* Whh = s == 0 ? P.e1_Whh : s == 1 ? P.e2_Whh : P.dec_Whh;
    const float* M1s = P.M1 + (size_t)s * 2304 * 16;
    __hip_bfloat16* Bp = s == 0 ? P.Bp1 : s == 1 ? P.Bp2 : P.Bp3;
    int k = r % 800, c = r / 800;
    int f = (c >> 4) & 3, u = (c >> 6) * 16 + (c & 15);
    float v = 0.f;
    if (k < 768) {
      if (f == 0) v = Whh[(size_t)u * 768 + k];
      else if (f == 1) v = Whh[(size_t)(768 + u) * 768 + k];
      else if (f == 3) v = Whh[(size_t)(1536 + u) * 768 + k];
    } else if (k < 784) {
      if (f < 3) v = M1s[(size_t)(f * 768 + u) * 16 + (k - 768)];
    }
    Bp[r] = __float2bfloat16(v);
  }
  gbar(P.bar);

  // ================= 26 sequential steps =================
  const int w = tid >> 6, l = tid & 63;
  const int nt = bid % 48, bm = bid / 48;
  const int rowA = bm * 128, colB = nt * 64;
  const int lr = l & 15, lk = l >> 4;
  const int wbase = w * 1024;
  const int rA = tid >> 2;
  const int ce = (((tid & 3) ^ ((tid >> 3) & 3)) << 3);   // swizzled source octet
  const int lks = ((lk ^ ((lr >> 1) & 3)) << 3);          // swizzled read octet

  for (int s = 0; s < 26; ++s) {
    const __hip_bfloat16* Bp = s < 7 ? P.Bp1 : s < 14 ? P.Bp2 : P.Bp3;
    const float* bias = P.biasP + (s < 7 ? 0 : s < 14 ? 3072 : 6144) + nt * 64;
    const __hip_bfloat16* g2a = (s >= 7 && s < 14) ? P.g2add : nullptr;
    const __hip_bfloat16* vel = s < 7   ? P.velall + (size_t)(6 - s) * (NB * 32)
                              : s < 14  ? P.velall + (size_t)(s - 7) * (NB * 32)
                              : s == 14 ? P.velall + (size_t)6 * (NB * 32)
                                        : P.dvel;
    const __hip_bfloat16* hin = (s == 0 || s == 7) ? nullptr : ((s & 1) ? P.hp0 : P.hp1);
    __hip_bfloat16* hout = (s & 1) ? P.hp1 : P.hp0;

    f32x4 acc[2][4];
#pragma unroll
    for (int m = 0; m < 2; ++m)
#pragma unroll
      for (int n = 0; n < 4; ++n) acc[m][n] = (f32x4){0.f, 0.f, 0.f, 0.f};

    auto STAGE = [&](int buf, int kb) {
#pragma unroll
      for (int i_ = 0; i_ < 2; ++i_) {
        int r_ = i_ * 64 + rA;
        const __hip_bfloat16* s_ = (kb < 768)
            ? hin + (size_t)(rowA + r_) * H + kb + ce
            : vel + (size_t)(rowA + r_) * 32 + ce;
        gload_lds16(s_, lds + buf * 12288 + i_ * 4096 + wbase);
      }
      gload_lds16(Bp + (size_t)(colB + rA) * 800 + kb + ce, lds + buf * 12288 + 8192 + wbase);
    };

    if (hin) {
      STAGE(0, 0);
      STAGE(1, 32);
      STAGE(2, 64);
#pragma unroll
      for (int ki = 0; ki < 25; ++ki) {
        if (ki < 23)       asm volatile("s_waitcnt vmcnt(6)" ::: "memory");
        else if (ki == 23) asm volatile("s_waitcnt vmcnt(3)" ::: "memory");
        else               asm volatile("s_waitcnt vmcnt(0)" ::: "memory");
        __builtin_amdgcn_sched_barrier(0);
        __builtin_amdgcn_s_barrier();
        __builtin_amdgcn_sched_barrier(0);
        if (ki < 22) STAGE((ki + 3) & 3, (ki + 3) * 32);
        const char* cur = lds + (ki & 3) * 12288;
        const __hip_bfloat16* Ab = (const __hip_bfloat16*)cur;
        const __hip_bfloat16* Bb = (const __hip_bfloat16*)(cur + 8192);
        bf16x8 a0 = *(const bf16x8*)(Ab + (w * 32 + lr) * 32 + lks);
        bf16x8 a1 = *(const bf16x8*)(Ab + (w * 32 + 16 + lr) * 32 + lks);
        bf16x8 b0 = *(const bf16x8*)(Bb + lr * 32 + lks);
        bf16x8 b1 = *(const bf16x8*)(Bb + (16 + lr) * 32 + lks);
        const bool last = (ki == 24);
        bf16x8 b2 = *(const bf16x8*)(Bb + ((last ? 32 : 48) + lr) * 32 + lks);
        __builtin_amdgcn_s_setprio(1);
        acc[0][0] = __builtin_amdgcn_mfma_f32_16x16x32_bf16(a0, b0, acc[0][0], 0, 0, 0);
        acc[1][0] = __builtin_amdgcn_mfma_f32_16x16x32_bf16(a1, b0, acc[1][0], 0, 0, 0);
        acc[0][1] = __builtin_amdgcn_mfma_f32_16x16x32_bf16(a0, b1, acc[0][1], 0, 0, 0);
        acc[1][1] = __builtin_amdgcn_mfma_f32_16x16x32_bf16(a1, b1, acc[1][1], 0, 0, 0);
        if (last) {
          acc[0][2] = __builtin_amdgcn_mfma_f32_16x16x32_bf16(a0, b2, acc[0][2], 0, 0, 0);
          acc[1][2] = __builtin_amdgcn_mfma_f32_16x16x32_bf16(a1, b2, acc[1][2], 0, 0, 0);
        } else {
          acc[0][3] = __builtin_amdgcn_mfma_f32_16x16x32_bf16(a0, b2, acc[0][3], 0, 0, 0);
          acc[1][3] = __builtin_amdgcn_mfma_f32_16x16x32_bf16(a1, b2, acc[1][3], 0, 0, 0);
        }
        __builtin_amdgcn_s_setprio(0);
      }
    } else {
      // h == 0: only the velocity K-chunk (kb=768) contributes
      STAGE(0, 768);
      asm volatile("s_waitcnt vmcnt(0)" ::: "memory");
      __builtin_amdgcn_sched_barrier(0);
      __builtin_amdgcn_s_barrier();
      __builtin_amdgcn_sched_barrier(0);
      const __hip_bfloat16* Ab = (const __hip_bfloat16*)lds;
      const __hip_bfloat16* Bb = (const __hip_bfloat16*)(lds + 8192);
      bf16x8 a0 = *(const bf16x8*)(Ab + (w * 32 + lr) * 32 + lks);
      bf16x8 a1 = *(const bf16x8*)(Ab + (w * 32 + 16 + lr) * 32 + lks);
      bf16x8 b0 = *(const bf16x8*)(Bb + lr * 32 + lks);
      bf16x8 b1 = *(const bf16x8*)(Bb + (16 + lr) * 32 + lks);
      bf16x8 b2 = *(const bf16x8*)(Bb + (32 + lr) * 32 + lks);
      acc[0][0] = __builtin_amdgcn_mfma_f32_16x16x32_bf16(a0, b0, acc[0][0], 0, 0, 0);
      acc[1][0] = __builtin_amdgcn_mfma_f32_16x16x32_bf16(a1, b0, acc[1][0], 0, 0, 0);
      acc[0][1] = __builtin_amdgcn_mfma_f32_16x16x32_bf16(a0, b1, acc[0][1], 0, 0, 0);
      acc[1][1] = __builtin_amdgcn_mfma_f32_16x16x32_bf16(a1, b1, acc[1][1], 0, 0, 0);
      acc[0][2] = __builtin_amdgcn_mfma_f32_16x16x32_bf16(a0, b2, acc[0][2], 0, 0, 0);
      acc[1][2] = __builtin_amdgcn_mfma_f32_16x16x32_bf16(a1, b2, acc[1][2], 0, 0, 0);
    }

    __syncthreads();
    // biased pre-activations to LDS tile [128][72]
    short* T = (short*)lds;
#pragma unroll
    for (int n = 0; n < 4; ++n) {
      float bv = bias[n * 16 + lr];
#pragma unroll
      for (int m = 0; m < 2; ++m) {
        int rbase = w * 32 + m * 16 + lk * 4;
#pragma unroll
        for (int r4 = 0; r4 < 4; ++r4)
          T[(rbase + r4) * 72 + n * 16 + lr] = f2bs(acc[m][n][r4] + bv);
      }
    }
    __syncthreads();

    // GRU epilogue: 128 rows x 16 units
    {
      const int row = tid >> 1;
      const int ub = (tid & 1) * 8;
      const size_t grow = (size_t)(rowA + row);
      const short* Tp = T + row * 72;
      bf16x8 Lr = *(const bf16x8*)(Tp + ub);
      bf16x8 Lz = *(const bf16x8*)(Tp + 16 + ub);
      bf16x8 Li = *(const bf16x8*)(Tp + 32 + ub);
      bf16x8 Lh = *(const bf16x8*)(Tp + 48 + ub);
      bf16x8 h8 = {};
      if (hin) h8 = *(const bf16x8*)(hin + grow * H + nt * 16 + ub);
      bf16x8 gr = {}, gz = {}, gi_ = {};
      if (g2a) {
        const __hip_bfloat16* gp = g2a + grow * 3072 + nt * 64;
        gr  = *(const bf16x8*)(gp + ub);
        gz  = *(const bf16x8*)(gp + 16 + ub);
        gi_ = *(const bf16x8*)(gp + 32 + ub);
      }
      union { bf16x8 v; short s[8]; } ob;
#pragma unroll
      for (int e = 0; e < 8; ++e) {
        float xr = b2f(Lr[e]), xz = b2f(Lz[e]), xi = b2f(Li[e]), xh = b2f(Lh[e]);
        if (g2a) { xr += b2f(gr[e]); xz += b2f(gz[e]); xi += b2f(gi_[e]); }
        float r = 1.f / (1.f + expf(-xr));
        float z = 1.f / (1.f + expf(-xz));
        float nn = tanhf(xi + r * xh);
        float hv = hin ? ((1.f - z) * nn + z * b2f(h8[e])) : ((1.f - z) * nn);
        ob.s[e] = f2bs(hv);
      }
      *(bf16x8*)(hout + grow * H + nt * 16 + ub) = ob.v;
    }
    gbar(P.bar);

    // ---- g2add = h_inv @ B2g^T after encoder-1 ----
    if (s == 6) {
      if (bid < 384) {
        const int bn = bid % 24, bmp = bid / 24;
        const int wm = w >> 1, wn = w & 1;
        __hip_bfloat16* Asm = (__hip_bfloat16*)lds;
        __hip_bfloat16* Bsm = (__hip_bfloat16*)(lds + 8192);
        f32x4 pa[4][4];
#pragma unroll
        for (int m = 0; m < 4; ++m)
#pragma unroll
          for (int n = 0; n < 4; ++n) pa[m][n] = (f32x4){0.f, 0.f, 0.f, 0.f};
        const int rAp = bmp * 128, rB = bn * 128;
        for (int kb = 0; kb < H; kb += 32) {
#pragma unroll
          for (int i = 0; i < 2; ++i) {
            int r = i * 64 + rA;
            gload_lds16(P.hp0 + (size_t)(rAp + r) * H + kb + ce, (char*)Asm + i * 4096 + wbase);
            gload_lds16(P.B2g + (size_t)(rB + r) * H + kb + ce, (char*)Bsm + i * 4096 + wbase);
          }
          __syncthreads();
          bf16x8 af[4], bfr[4];
#pragma unroll
          for (int m = 0; m < 4; ++m)
            af[m] = *(const bf16x8*)(Asm + (wm * 64 + m * 16 + lr) * 32 + lks);
#pragma unroll
          for (int n = 0; n < 4; ++n)
            bfr[n] = *(const bf16x8*)(Bsm + (wn * 64 + n * 16 + lr) * 32 + lks);
#pragma unroll
          for (int m = 0; m < 4; ++m)
#pragma unroll
            for (int n = 0; n < 4; ++n)
              pa[m][n] = __builtin_amdgcn_mfma_f32_16x16x32_bf16(af[m], bfr[n], pa[m][n], 0, 0, 0);
          __syncthreads();
        }
#pragma unroll
        for (int m = 0; m < 4; ++m)
#pragma unroll
          for (int n = 0; n < 4; ++n) {
            int col = bn * 128 + wn * 64 + n * 16 + lr;
#pragma unroll
            for (int r4 = 0; r4 < 4; ++r4) {
              int row = rAp + wm * 64 + m * 16 + lk * 4 + r4;
              P.g2add[(size_t)row * 3072 + col] = __float2bfloat16(pa[m][n][r4]);
            }
          }
      }
      gbar(P.bar);
    }

    // ---- decoder head ----
    if (s >= 14) {
      int k = s - 14;
      if (bid < 512) {
        const int wv = tid >> 6, lane = tid & 63;
        const int row = bid * 4 + wv;
        const short* hs = (const short*)hout;
        const float* o2 = (k == 0) ? P.observed + (size_t)7 * NB * DD
                                   : P.pred + (size_t)(k - 1) * NB * DD;
        float* relo = P.rel + (size_t)k * NB * 5;
        float* poso = P.pred + (size_t)k * NB * DD;
        float s0 = 0.f, s1 = 0.f, s2 = 0.f, s3 = 0.f, s4 = 0.f;
        for (int kk = lane; kk < H; kk += 64) {
          float hv = b2f(hs[(size_t)row * H + kk]);
          s0 += hv * P.h2n_W[kk];
          s1 += hv * P.h2n_W[H + kk];
          s2 += hv * P.h2n_W[2 * H + kk];
          s3 += hv * P.h2n_W[3 * H + kk];
          s4 += hv * P.h2n_W[4 * H + kk];
        }
#pragma unroll
        for (int off = 32; off; off >>= 1) {
          s0 += __shfl_down(s0, off);
          s1 += __shfl_down(s1, off);
          s2 += __shfl_down(s2, off);
          s3 += __shfl_down(s3, off);
          s4 += __shfl_down(s4, off);
        }
        s0 = __shfl(s0, 0); s1 = __shfl(s1, 0); s2 = __shfl(s2, 0);
        s3 = __shfl(s3, 0); s4 = __shfl(s4, 0);
        float n0 = s0 + P.h2n_b[0], n1 = s1 + P.h2n_b[1];
        float x2 = s2 + P.h2n_b[2], x3 = s3 + P.h2n_b[3], x4 = s4 + P.h2n_b[4];
        float n2 = 0.01f + 0.2f * (x2 > 0.f ? x2 + log1pf(expf(-x2)) : log1pf(expf(x2)));
        float n3 = 0.01f + 0.2f * (x3 > 0.f ? x3 + log1pf(expf(-x3)) : log1pf(expf(x3)));
        float n4 = 0.7f * tanhf(x4);
        float rl = 0.f;
        if (lane < DD) {
          float a = P.mix_b[lane] + n0 * P.mix_W[lane * 5 + 0] + n1 * P.mix_W[lane * 5 + 1] +
                    n2 * P.mix_W[lane * 5 + 2] + n3 * P.mix_W[lane * 5 + 3] +
                    n4 * P.mix_W[lane * 5 + 4];
          rl = a > 0.f ? a : 0.f;
          poso[(size_t)row * DD + lane] = o2[(size_t)row * DD + lane] + rl;
        }
        if (lane < 32)
          P.dvel[(size_t)row * 32 + lane] = __float2bfloat16(lane < DD ? rl : 0.f);
        if (lane == 0) {
          relo[(size_t)row * 5 + 0] = n0;
          relo[(size_t)row * 5 + 1] = n1;
          relo[(size_t)row * 5 + 2] = n2;
          relo[(size_t)row * 5 + 3] = n3;
          relo[(size_t)row * 5 + 4] = n4;
        }
      }
      gbar(P.bar);
    }
  }
}

extern "C" void kernel_launch(void* const* d_in, const int* in_sizes, int n_in,
                              void* d_out, int out_size, void* d_ws, size_t ws_size,
                              hipStream_t stream) {
  (void)in_sizes; (void)n_in; (void)out_size; (void)ws_size;
  char* p = (char*)d_ws;
  auto alloc = [&](size_t bytes) { char* r = p; p += (bytes + 255) & ~(size_t)255; return r; };

  KP P;
  P.observed = (const float*)d_in[0];
  P.emb_W   = (const float*)d_in[1];
  P.emb_b   = (const float*)d_in[2];
  P.e1_Wih  = (const float*)d_in[3];
  P.e1_Whh  = (const float*)d_in[4];
  P.e1_bih  = (const float*)d_in[5];
  P.e1_bhh  = (const float*)d_in[6];
  P.e2_Wih  = (const float*)d_in[7];
  P.e2_Whh  = (const float*)d_in[8];
  P.e2_bih  = (const float*)d_in[9];
  P.e2_bhh  = (const float*)d_in[10];
  P.dec_Wih = (const float*)d_in[11];
  P.dec_Whh = (const float*)d_in[12];
  P.dec_bih = (const float*)d_in[13];
  P.dec_bhh = (const float*)d_in[14];
  P.h2n_W   = (const float*)d_in[15];
  P.h2n_b   = (const float*)d_in[16];
  P.mix_W   = (const float*)d_in[17];
  P.mix_b   = (const float*)d_in[18];

  P.hp0    = (__hip_bfloat16*)alloc((size_t)NB * H * 2);
  P.hp1    = (__hip_bfloat16*)alloc((size_t)NB * H * 2);
  P.velall = (__hip_bfloat16*)alloc((size_t)7 * NB * 32 * 2);
  P.dvel   = (__hip_bfloat16*)alloc((size_t)NB * 32 * 2);
  P.Bp1    = (__hip_bfloat16*)alloc((size_t)3072 * 800 * 2);
  P.Bp2    = (__hip_bfloat16*)alloc((size_t)3072 * 800 * 2);
  P.Bp3    = (__hip_bfloat16*)alloc((size_t)3072 * 800 * 2);
  P.B2g    = (__hip_bfloat16*)alloc((size_t)3072 * 768 * 2);
  P.g2add  = (__hip_bfloat16*)alloc((size_t)NB * 3072 * 2);
  P.M1     = (float*)alloc((size_t)3 * 2304 * 16 * 4);
  P.biasP  = (float*)alloc((size_t)3 * 3072 * 4);
  P.bar    = (int*)alloc(2048);

  P.rel  = (float*)d_out;                        // (12, 2048, 5)
  P.pred = (float*)d_out + (size_t)12 * NB * 5;  // (12, 2048, 16)

  hipMemsetAsync(P.bar, 0, 2048, stream);
  k_all<<<dim3(NBLK), dim3(256), 0, stream>>>(P);
}

// Round 7
// 801.934 us; speedup vs baseline: 12.0184x; 12.0184x over previous
//
#include <hip/hip_runtime.h>
#include <hip/hip_bf16.h>
#include <math.h>

#define H 768
#define NB 2048
#define DD 16
// packed gate matrix: 3072 cols = 48 tiles x (16 r | 16 z | 16 in | 16 hn), K = 800 = 768 h + 16 vel + 16 pad

typedef __attribute__((ext_vector_type(8))) short bf16x8;
typedef __attribute__((ext_vector_type(4))) short bf16x4;
typedef __attribute__((ext_vector_type(4))) float f32x4;

__device__ __forceinline__ void gload_lds16(const void* g, void* lds) {
  __builtin_amdgcn_global_load_lds((const __attribute__((address_space(1))) void*)g,
                                   (__attribute__((address_space(3))) void*)lds, 16, 0, 0);
}
__device__ __forceinline__ float b2f(short s) {
  union { unsigned int u; float f; } c;
  c.u = ((unsigned int)(unsigned short)s) << 16;
  return c.f;
}
__device__ __forceinline__ short f2bs(float f) {
  __hip_bfloat16 h = __float2bfloat16(f);
  return *(short*)&h;
}

// ---------- M1[s][g][d] = 4 * sum_e Wih_s[g][e] * emb_W[e][d] ----------
__global__ void k_m1(const float* __restrict__ e1W, const float* __restrict__ e2W,
                     const float* __restrict__ dW, const float* __restrict__ embW,
                     float* __restrict__ M1) {
  int idx = blockIdx.x * 256 + threadIdx.x;  // < 3*2304*16
  if (idx >= 3 * 2304 * 16) return;
  int d = idx & 15, g = (idx >> 4) % 2304, s = idx / (2304 * 16);
  const float* W = s == 0 ? e1W : s == 1 ? e2W : dW;
  int ld = s == 1 ? 1024 : 256;
  float sum = 0.f;
  for (int e = 0; e < 256; ++e) sum += W[(size_t)g * ld + e] * embW[e * 16 + d];
  M1[idx] = 4.0f * sum;
}

// ---------- packed bias [3][3072]: embeds emb_b fold ----------
__global__ void k_biasP(const float* __restrict__ e1W, const float* __restrict__ e2W,
                        const float* __restrict__ dW, const float* __restrict__ embB,
                        const float* b1i, const float* b1h, const float* b2i, const float* b2h,
                        const float* b3i, const float* b3h, float* __restrict__ out) {
  int idx = blockIdx.x * 256 + threadIdx.x;  // < 3*3072
  if (idx >= 3 * 3072) return;
  int c = idx % 3072, s = idx / 3072;
  int f = (c >> 4) & 3, u = (c >> 6) * 16 + (c & 15);
  const float* W = s == 0 ? e1W : s == 1 ? e2W : dW;
  int ld = s == 1 ? 1024 : 256;
  const float* bi = s == 0 ? b1i : s == 1 ? b2i : b3i;
  const float* bh = s == 0 ? b1h : s == 1 ? b2h : b3h;
  float v;
  if (f == 3) {
    v = bh[1536 + u];
  } else {
    int g = (f < 2 ? f * 768 : 1536) + u;
    float acc = bi[g] + (f < 2 ? bh[g] : 0.f);
    for (int e = 0; e < 256; ++e) acc += W[(size_t)g * ld + e] * embB[e];
    v = acc;
  }
  out[idx] = v;
}

// ---------- pack 3 weight sets -> Bp[3072][800] bf16 (grid.y selects set) ----------
__global__ void k_packB3(const float* __restrict__ W1, const float* __restrict__ W2,
                         const float* __restrict__ W3, const float* __restrict__ M1all,
                         __hip_bfloat16* __restrict__ B1, __hip_bfloat16* __restrict__ B2,
                         __hip_bfloat16* __restrict__ B3) {
  int idx = blockIdx.x * 256 + threadIdx.x;  // < 3072*800
  if (idx >= 3072 * 800) return;
  int s = blockIdx.y;
  const float* Whh = s == 0 ? W1 : s == 1 ? W2 : W3;
  const float* M1s = M1all + (size_t)s * 2304 * 16;
  __hip_bfloat16* Bp = s == 0 ? B1 : s == 1 ? B2 : B3;
  int k = idx % 800, c = idx / 800;
  int f = (c >> 4) & 3, u = (c >> 6) * 16 + (c & 15);
  float v = 0.f;
  if (k < 768) {
    if (f == 0) v = Whh[(size_t)u * 768 + k];
    else if (f == 1) v = Whh[(size_t)(768 + u) * 768 + k];
    else if (f == 3) v = Whh[(size_t)(1536 + u) * 768 + k];
  } else if (k < 784) {
    if (f < 3) v = M1s[(size_t)(f * 768 + u) * 16 + (k - 768)];
  }
  Bp[idx] = __float2bfloat16(v);
}

// ---------- pack e2_Wih[:,256:] into interleaved order -> B2g[3072][768] ----------
__global__ void k_packB2g(const float* __restrict__ e2W, __hip_bfloat16* __restrict__ B2g) {
  int idx = blockIdx.x * 256 + threadIdx.x;  // < 3072*768
  if (idx >= 3072 * 768) return;
  int k = idx % 768, c = idx / 768;
  int f = (c >> 4) & 3, u = (c >> 6) * 16 + (c & 15);
  float v = (f < 3) ? e2W[(size_t)(f * 768 + u) * 1024 + 256 + k] : 0.f;
  B2g[idx] = __float2bfloat16(v);
}

// ---------- velocities for 7 frames, zero-padded to 32 ----------
__global__ void k_vel(const float* __restrict__ obs, __hip_bfloat16* __restrict__ velall) {
  int idx = blockIdx.x * 256 + threadIdx.x;  // < 7*2048*32
  if (idx >= 7 * 2048 * 32) return;
  int d = idx & 31, n = (idx >> 5) & 2047, s = idx >> 16;
  float v = 0.f;
  if (d < 16)
    v = obs[((size_t)(s + 1) * NB + n) * DD + d] - obs[((size_t)s * NB + n) * DD + d];
  velall[idx] = __float2bfloat16(v);
}

// ---------- plain GEMM for g2add: C[2048][3072] = A(2048x768) @ B(3072x768)^T ----------
__global__ __launch_bounds__(256) void k_plain(
    const __hip_bfloat16* __restrict__ A, const __hip_bfloat16* __restrict__ B,
    __hip_bfloat16* __restrict__ C, int ldc) {
  __shared__ __align__(16) __hip_bfloat16 Asm[128 * 32];
  __shared__ __align__(16) __hip_bfloat16 Bsm[128 * 32];
  const int tid = threadIdx.x;
  const int w = tid >> 6, l = tid & 63;
  const int bm = blockIdx.y, bn = blockIdx.x;
  const int wm = w >> 1, wn = w & 1;
  const int lr = l & 15, lk = l >> 4;
  const int ks = (((tid & 3) ^ ((tid >> 3) & 3)) << 3);
  const int lks = ((lk ^ ((lr >> 1) & 3)) << 3);
  f32x4 acc[4][4];
#pragma unroll
  for (int m = 0; m < 4; ++m)
#pragma unroll
    for (int n = 0; n < 4; ++n) acc[m][n] = (f32x4){0.f, 0.f, 0.f, 0.f};
  const int rowA = bm * 128, rowB = bn * 128;
  const int rA = tid >> 2;
  for (int kb = 0; kb < H; kb += 32) {
#pragma unroll
    for (int i = 0; i < 2; ++i) {
      int r = i * 64 + rA;
      gload_lds16(A + (size_t)(rowA + r) * H + kb + ks, (char*)Asm + i * 4096 + w * 1024);
      gload_lds16(B + (size_t)(rowB + r) * H + kb + ks, (char*)Bsm + i * 4096 + w * 1024);
    }
    __syncthreads();
    bf16x8 af[4], bfr[4];
#pragma unroll
    for (int m = 0; m < 4; ++m)
      af[m] = *(const bf16x8*)(Asm + (wm * 64 + m * 16 + lr) * 32 + lks);
#pragma unroll
    for (int n = 0; n < 4; ++n)
      bfr[n] = *(const bf16x8*)(Bsm + (wn * 64 + n * 16 + lr) * 32 + lks);
#pragma unroll
    for (int m = 0; m < 4; ++m)
#pragma unroll
      for (int n = 0; n < 4; ++n)
        acc[m][n] = __builtin_amdgcn_mfma_f32_16x16x32_bf16(af[m], bfr[n], acc[m][n], 0, 0, 0);
    __syncthreads();
  }
#pragma unroll
  for (int m = 0; m < 4; ++m)
#pragma unroll
    for (int n = 0; n < 4; ++n) {
      int col = bn * 128 + wn * 64 + n * 16 + lr;
#pragma unroll
      for (int r4 = 0; r4 < 4; ++r4) {
        int row = rowA + wm * 64 + m * 16 + lk * 4 + r4;
        C[(size_t)row * ldc + col] = __float2bfloat16(acc[m][n][r4]);
      }
    }
}

// ---------- fused step: 64x64 tile, 5-deep ring, counted vmcnt, GRU epilogue ----------
// grid (48, 32), 256 threads, 40KB LDS -> 4 blocks/CU.
__global__ __launch_bounds__(256, 4) void k_step(
    const __hip_bfloat16* __restrict__ hin,  // 2048 x 768 or null (h=0 step)
    const __hip_bfloat16* __restrict__ vel,  // 2048 x 32
    const __hip_bfloat16* __restrict__ Bp,   // 3072 x 800
    const float* __restrict__ bias,          // 3072 packed (set base)
    const __hip_bfloat16* __restrict__ g2a,  // 2048 x 3072 interleaved or null
    __hip_bfloat16* __restrict__ hout) {     // 2048 x 768
  __shared__ __align__(16) char lds[40960];  // 5 bufs x (A 4KB + B 4KB)
  const int tid = threadIdx.x;
  const int w = tid >> 6, l = tid & 63;
  const int nt = blockIdx.x, bm = blockIdx.y;
  const int rowA = bm * 64, colB = nt * 64;
  const int lr = l & 15, lk = l >> 4;
  const int wm = w >> 1, wn = w & 1;
  const int rS = tid >> 2;                                 // staged row, 4 threads/row
  const int ce = (((tid & 3) ^ ((tid >> 3) & 3)) << 3);    // swizzled source octet
  const int lks = ((lk ^ ((lr >> 1) & 3)) << 3);           // swizzled read octet
  const int wbase = w * 1024;

  auto STAGE = [&](int buf, int kb) {
    const __hip_bfloat16* s_ = (kb < 768)
        ? hin + (size_t)(rowA + rS) * H + kb + ce
        : vel + (size_t)(rowA + rS) * 32 + ce;
    gload_lds16(s_, lds + buf * 8192 + wbase);
    gload_lds16(Bp + (size_t)(colB + rS) * 800 + kb + ce, lds + buf * 8192 + 4096 + wbase);
  };

  f32x4 acc[2][2];
#pragma unroll
  for (int m = 0; m < 2; ++m)
#pragma unroll
    for (int n = 0; n < 2; ++n) acc[m][n] = (f32x4){0.f, 0.f, 0.f, 0.f};

  if (hin) {
    STAGE(0, 0); STAGE(1, 32); STAGE(2, 64); STAGE(3, 96);
#pragma unroll
    for (int ki = 0; ki < 25; ++ki) {
      if (ki < 22)       asm volatile("s_waitcnt vmcnt(6)" ::: "memory");
      else if (ki == 22) asm volatile("s_waitcnt vmcnt(4)" ::: "memory");
      else if (ki == 23) asm volatile("s_waitcnt vmcnt(2)" ::: "memory");
      else               asm volatile("s_waitcnt vmcnt(0)" ::: "memory");
      __builtin_amdgcn_sched_barrier(0);
      __builtin_amdgcn_s_barrier();
      __builtin_amdgcn_sched_barrier(0);
      if (ki < 21) STAGE((ki + 4) % 5, (ki + 4) * 32);
      const char* cur = lds + (ki % 5) * 8192;
      const __hip_bfloat16* Ab = (const __hip_bfloat16*)cur;
      const __hip_bfloat16* Bb = (const __hip_bfloat16*)(cur + 4096);
      bf16x8 a0 = *(const bf16x8*)(Ab + (wm * 32 + lr) * 32 + lks);
      bf16x8 a1 = *(const bf16x8*)(Ab + (wm * 32 + 16 + lr) * 32 + lks);
      bf16x8 b0 = *(const bf16x8*)(Bb + (wn * 32 + lr) * 32 + lks);
      bf16x8 b1 = *(const bf16x8*)(Bb + (wn * 32 + 16 + lr) * 32 + lks);
      __builtin_amdgcn_s_setprio(1);
      acc[0][0] = __builtin_amdgcn_mfma_f32_16x16x32_bf16(a0, b0, acc[0][0], 0, 0, 0);
      acc[1][0] = __builtin_amdgcn_mfma_f32_16x16x32_bf16(a1, b0, acc[1][0], 0, 0, 0);
      acc[0][1] = __builtin_amdgcn_mfma_f32_16x16x32_bf16(a0, b1, acc[0][1], 0, 0, 0);
      acc[1][1] = __builtin_amdgcn_mfma_f32_16x16x32_bf16(a1, b1, acc[1][1], 0, 0, 0);
      __builtin_amdgcn_s_setprio(0);
    }
  } else {
    // h == 0: only the velocity K-chunk (kb=768); hn cols are zero in Bp there.
    STAGE(0, 768);
    asm volatile("s_waitcnt vmcnt(0)" ::: "memory");
    __builtin_amdgcn_sched_barrier(0);
    __builtin_amdgcn_s_barrier();
    __builtin_amdgcn_sched_barrier(0);
    const __hip_bfloat16* Ab = (const __hip_bfloat16*)lds;
    const __hip_bfloat16* Bb = (const __hip_bfloat16*)(lds + 4096);
    bf16x8 a0 = *(const bf16x8*)(Ab + (wm * 32 + lr) * 32 + lks);
    bf16x8 a1 = *(const bf16x8*)(Ab + (wm * 32 + 16 + lr) * 32 + lks);
    bf16x8 b0 = *(const bf16x8*)(Bb + (wn * 32 + lr) * 32 + lks);
    bf16x8 b1 = *(const bf16x8*)(Bb + (wn * 32 + 16 + lr) * 32 + lks);
    acc[0][0] = __builtin_amdgcn_mfma_f32_16x16x32_bf16(a0, b0, acc[0][0], 0, 0, 0);
    acc[1][0] = __builtin_amdgcn_mfma_f32_16x16x32_bf16(a1, b0, acc[1][0], 0, 0, 0);
    acc[0][1] = __builtin_amdgcn_mfma_f32_16x16x32_bf16(a0, b1, acc[0][1], 0, 0, 0);
    acc[1][1] = __builtin_amdgcn_mfma_f32_16x16x32_bf16(a1, b1, acc[1][1], 0, 0, 0);
  }

  __syncthreads();
  // biased pre-activations -> LDS tile [64][72] bf16
  short* T = (short*)lds;
#pragma unroll
  for (int n = 0; n < 2; ++n) {
    float bv = bias[colB + wn * 32 + n * 16 + lr];
#pragma unroll
    for (int m = 0; m < 2; ++m) {
      int rbase = wm * 32 + m * 16 + lk * 4;
#pragma unroll
      for (int r4 = 0; r4 < 4; ++r4)
        T[(rbase + r4) * 72 + wn * 32 + n * 16 + lr] = f2bs(acc[m][n][r4] + bv);
    }
  }
  __syncthreads();

  // GRU: 64 rows x 16 units; 256 threads x 4 units
  const int row = tid >> 2, q = tid & 3;
  const size_t grow = (size_t)(rowA + row);
  const short* Tp = T + row * 72;
  bf16x4 Lr = *(const bf16x4*)(Tp + q * 4);
  bf16x4 Lz = *(const bf16x4*)(Tp + 16 + q * 4);
  bf16x4 Li = *(const bf16x4*)(Tp + 32 + q * 4);
  bf16x4 Lh = *(const bf16x4*)(Tp + 48 + q * 4);
  bf16x4 h8 = {};
  if (hin) h8 = *(const bf16x4*)(hin + grow * H + colB / 4 + q * 4);
  bf16x4 gr = {}, gz = {}, gi_ = {};
  if (g2a) {
    const __hip_bfloat16* gp = g2a + grow * 3072 + colB;
    gr  = *(const bf16x4*)(gp + q * 4);
    gz  = *(const bf16x4*)(gp + 16 + q * 4);
    gi_ = *(const bf16x4*)(gp + 32 + q * 4);
  }
  union { bf16x4 v; short s[4]; } ob;
#pragma unroll
  for (int e = 0; e < 4; ++e) {
    float xr = b2f(Lr[e]), xz = b2f(Lz[e]), xi = b2f(Li[e]), xh = b2f(Lh[e]);
    if (g2a) { xr += b2f(gr[e]); xz += b2f(gz[e]); xi += b2f(gi_[e]); }
    float r = 1.f / (1.f + expf(-xr));
    float z = 1.f / (1.f + expf(-xz));
    float nn = tanhf(xi + r * xh);
    float hv = hin ? ((1.f - z) * nn + z * b2f(h8[e])) : ((1.f - z) * nn);
    ob.s[e] = f2bs(hv);
  }
  *(bf16x4*)(hout + grow * H + colB / 4 + q * 4) = ob.v;
}

// ---------- decoder head ----------
__global__ void k_head(const __hip_bfloat16* __restrict__ h, const float* __restrict__ obs2,
                       const float* __restrict__ h2n_W, const float* __restrict__ h2n_b,
                       const float* __restrict__ mix_W, const float* __restrict__ mix_b,
                       float* __restrict__ rel_out, float* __restrict__ pos_out,
                       __hip_bfloat16* __restrict__ velout) {
  int wv = threadIdx.x >> 6, lane = threadIdx.x & 63;
  int row = blockIdx.x * 4 + wv;
  float s0 = 0.f, s1 = 0.f, s2 = 0.f, s3 = 0.f, s4 = 0.f;
  for (int k = lane; k < H; k += 64) {
    float hv = b2f(((const short*)h)[(size_t)row * H + k]);
    s0 += hv * h2n_W[k];
    s1 += hv * h2n_W[H + k];
    s2 += hv * h2n_W[2 * H + k];
    s3 += hv * h2n_W[3 * H + k];
    s4 += hv * h2n_W[4 * H + k];
  }
#pragma unroll
  for (int off = 32; off; off >>= 1) {
    s0 += __shfl_down(s0, off);
    s1 += __shfl_down(s1, off);
    s2 += __shfl_down(s2, off);
    s3 += __shfl_down(s3, off);
    s4 += __shfl_down(s4, off);
  }
  s0 = __shfl(s0, 0); s1 = __shfl(s1, 0); s2 = __shfl(s2, 0);
  s3 = __shfl(s3, 0); s4 = __shfl(s4, 0);
  float n0 = s0 + h2n_b[0], n1 = s1 + h2n_b[1];
  float x2 = s2 + h2n_b[2], x3 = s3 + h2n_b[3], x4 = s4 + h2n_b[4];
  float n2 = 0.01f + 0.2f * (x2 > 0.f ? x2 + log1pf(expf(-x2)) : log1pf(expf(x2)));
  float n3 = 0.01f + 0.2f * (x3 > 0.f ? x3 + log1pf(expf(-x3)) : log1pf(expf(x3)));
  float n4 = 0.7f * tanhf(x4);
  float rl = 0.f;
  if (lane < DD) {
    float a = mix_b[lane] + n0 * mix_W[lane * 5 + 0] + n1 * mix_W[lane * 5 + 1] +
              n2 * mix_W[lane * 5 + 2] + n3 * mix_W[lane * 5 + 3] + n4 * mix_W[lane * 5 + 4];
    rl = a > 0.f ? a : 0.f;
    pos_out[(size_t)row * DD + lane] = obs2[(size_t)row * DD + lane] + rl;
  }
  if (lane < 32)
    velout[(size_t)row * 32 + lane] = __float2bfloat16(lane < DD ? rl : 0.f);
  if (lane == 0) {
    rel_out[(size_t)row * 5 + 0] = n0;
    rel_out[(size_t)row * 5 + 1] = n1;
    rel_out[(size_t)row * 5 + 2] = n2;
    rel_out[(size_t)row * 5 + 3] = n3;
    rel_out[(size_t)row * 5 + 4] = n4;
  }
}

extern "C" void kernel_launch(void* const* d_in, const int* in_sizes, int n_in,
                              void* d_out, int out_size, void* d_ws, size_t ws_size,
                              hipStream_t stream) {
  (void)in_sizes; (void)n_in; (void)out_size; (void)ws_size;
  const float* observed = (const float*)d_in[0];
  const float* emb_W   = (const float*)d_in[1];
  const float* emb_b   = (const float*)d_in[2];
  const float* e1_Wih  = (const float*)d_in[3];
  const float* e1_Whh  = (const float*)d_in[4];
  const float* e1_bih  = (const float*)d_in[5];
  const float* e1_bhh  = (const float*)d_in[6];
  const float* e2_Wih  = (const float*)d_in[7];
  const float* e2_Whh  = (const float*)d_in[8];
  const float* e2_bih  = (const float*)d_in[9];
  const float* e2_bhh  = (const float*)d_in[10];
  const float* dec_Wih = (const float*)d_in[11];
  const float* dec_Whh = (const float*)d_in[12];
  const float* dec_bih = (const float*)d_in[13];
  const float* dec_bhh = (const float*)d_in[14];
  const float* h2n_W   = (const float*)d_in[15];
  const float* h2n_b   = (const float*)d_in[16];
  const float* mix_W   = (const float*)d_in[17];
  const float* mix_b   = (const float*)d_in[18];

  char* p = (char*)d_ws;
  auto alloc = [&](size_t bytes) { char* r = p; p += (bytes + 255) & ~(size_t)255; return r; };

  __hip_bfloat16* hp0    = (__hip_bfloat16*)alloc((size_t)NB * H * 2);
  __hip_bfloat16* hp1    = (__hip_bfloat16*)alloc((size_t)NB * H * 2);
  __hip_bfloat16* velall = (__hip_bfloat16*)alloc((size_t)7 * NB * 32 * 2);
  __hip_bfloat16* dvel   = (__hip_bfloat16*)alloc((size_t)NB * 32 * 2);
  __hip_bfloat16* Bp1    = (__hip_bfloat16*)alloc((size_t)3072 * 800 * 2);
  __hip_bfloat16* Bp2    = (__hip_bfloat16*)alloc((size_t)3072 * 800 * 2);
  __hip_bfloat16* Bp3    = (__hip_bfloat16*)alloc((size_t)3072 * 800 * 2);
  __hip_bfloat16* B2g    = (__hip_bfloat16*)alloc((size_t)3072 * 768 * 2);
  __hip_bfloat16* g2add  = (__hip_bfloat16*)alloc((size_t)NB * 3072 * 2);
  float*          M1     = (float*)alloc((size_t)3 * 2304 * 16 * 4);
  float*          biasP  = (float*)alloc((size_t)3 * 3072 * 4);

  // ---- prep ----
  k_m1<<<(3 * 2304 * 16 + 255) / 256, 256, 0, stream>>>(e1_Wih, e2_Wih, dec_Wih, emb_W, M1);
  k_biasP<<<(3 * 3072 + 255) / 256, 256, 0, stream>>>(e1_Wih, e2_Wih, dec_Wih, emb_b,
                                                      e1_bih, e1_bhh, e2_bih, e2_bhh,
                                                      dec_bih, dec_bhh, biasP);
  k_packB3<<<dim3((3072 * 800 + 255) / 256, 3), 256, 0, stream>>>(e1_Whh, e2_Whh, dec_Whh,
                                                                  M1, Bp1, Bp2, Bp3);
  k_packB2g<<<(3072 * 768 + 255) / 256, 256, 0, stream>>>(e2_Wih, B2g);
  k_vel<<<(7 * NB * 32 + 255) / 256, 256, 0, stream>>>(observed, velall);

  dim3 gs(48, 32);
  const __hip_bfloat16* src = nullptr;
  __hip_bfloat16* dst = hp0;

  // ---- encoder 1: velocity frames 6,5,...,0 (t=0 has h=0) ----
  for (int t = 0; t < 7; ++t) {
    k_step<<<gs, 256, 0, stream>>>(t == 0 ? nullptr : src,
                                   velall + (size_t)(6 - t) * NB * 32, Bp1, biasP,
                                   nullptr, dst);
    src = dst;
    dst = (dst == hp0) ? hp1 : hp0;
  }
  // src = h_inv (hp0). g2add = h_inv @ B2g^T, interleaved layout
  k_plain<<<dim3(24, 16), 256, 0, stream>>>(src, B2g, g2add, 3072);

  // ---- encoder 2: frames 0..6 (t=0 has h=0) ----
  for (int t = 0; t < 7; ++t) {
    k_step<<<gs, 256, 0, stream>>>(t == 0 ? nullptr : src,
                                   velall + (size_t)t * NB * 32, Bp2, biasP + 3072,
                                   g2add, dst);
    src = dst;
    dst = (dst == hp0) ? hp1 : hp0;
  }

  // ---- decoder ----
  float* rel  = (float*)d_out;                       // (12, 2048, 5)
  float* pred = (float*)d_out + (size_t)12 * NB * 5; // (12, 2048, 16)
  for (int k = 0; k < 12; ++k) {
    const __hip_bfloat16* vk = (k == 0) ? velall + (size_t)6 * NB * 32 : dvel;
    k_step<<<gs, 256, 0, stream>>>(src, vk, Bp3, biasP + 2 * 3072, nullptr, dst);
    const float* o2 = (k == 0) ? observed + (size_t)7 * NB * DD
                               : pred + (size_t)(k - 1) * NB * DD;
    k_head<<<NB / 4, 256, 0, stream>>>(dst, o2, h2n_W, h2n_b, mix_W, mix_b,
                                       rel + (size_t)k * NB * 5, pred + (size_t)k * NB * DD,
                                       dvel);
    src = dst;
    dst = (dst == hp0) ? hp1 : hp0;
  }
}